// Round 3
// baseline (82.804 us; speedup 1.0000x reference)
//
#include <hip/hip_runtime.h>
#include <math.h>

// 4-qubit real statevector QNN, one thread per sample (verified structure).
//
// *** ROUND-2 MEASUREMENT PROBE — REMOVE BEFORE FINAL ***
// The timed region is dominated by harness reset fills (268 MB @ 80% HBM peak
// = ~42 us/iter); our kernel is <41 us and invisible in the top-5 counter
// rows. This version appends PROBE_PASSES extra perturbed circuit passes,
// results kept live via asm-volatile sinks (DCE-proof, CSE-proof via
// perturbed inputs). dur_us delta vs 75.4 measures the kernel's true ALU
// time: delta ~ +8 us => kernel ~5 us (harness floor, we're done);
// delta ~ +40 us => kernel ~25-30 us (real headroom, and the kernel will
// surface in the top-5 WITH counters).

#define PROBE_PASSES 2

template <int Q>
__device__ __forceinline__ void apply_ry(float* s, float c, float sn) {
    constexpr int stride = 1 << (3 - Q);
#pragma unroll
    for (int i = 0; i < 16; ++i) {
        if (!(i & stride)) {
            float a0 = s[i];
            float a1 = s[i + stride];
            s[i]          = c * a0 - sn * a1;
            s[i + stride] = sn * a0 + c * a1;
        }
    }
}

template <int C, int T>
__device__ __forceinline__ void cnot_(float* s) {
    constexpr int cs = 1 << (3 - C);
    constexpr int ts = 1 << (3 - T);
#pragma unroll
    for (int i = 0; i < 16; ++i) {
        if ((i & cs) && !(i & ts)) {
            float tmp = s[i];
            s[i] = s[i + ts];
            s[i + ts] = tmp;
        }
    }
}

__device__ __forceinline__ float bcast_lane(float v, int lane) {
    return __int_as_float(__builtin_amdgcn_readlane(__float_as_int(v), lane));
}

__device__ __forceinline__ void run_circuit(float* s, const float* cw, const float* sw) {
    apply_ry<0>(s, cw[0], sw[0]);
    apply_ry<1>(s, cw[1], sw[1]);
    apply_ry<2>(s, cw[2], sw[2]);
    apply_ry<3>(s, cw[3], sw[3]);
    cnot_<0,1>(s); cnot_<1,2>(s); cnot_<2,3>(s); cnot_<3,0>(s);
    apply_ry<0>(s, cw[4], sw[4]);
    apply_ry<1>(s, cw[5], sw[5]);
    apply_ry<2>(s, cw[6], sw[6]);
    apply_ry<3>(s, cw[7], sw[7]);
    cnot_<0,1>(s); cnot_<1,2>(s); cnot_<2,3>(s); cnot_<3,0>(s);
    apply_ry<0>(s, cw[8],  sw[8]);
    apply_ry<1>(s, cw[9],  sw[9]);
    apply_ry<2>(s, cw[10], sw[10]);
    apply_ry<3>(s, cw[11], sw[11]);
}

__global__ __launch_bounds__(256) void qnn_kernel(
    const float* __restrict__ x,     // [B,4]
    const float* __restrict__ qw,    // [3,4] trainable angles (uniform)
    const float* __restrict__ W,     // [6,4]
    const float* __restrict__ bias,  // [6]
    float* __restrict__ out,         // [B,6]
    int B)
{
    int b = blockIdx.x * blockDim.x + threadIdx.x;
    if (b >= B) return;
    int lane = threadIdx.x & 63;

    // --- uniform trainable-angle trig: lanes 0..11 each do ONE sincos,
    //     broadcast via readlane -> SGPR-resident uniforms ---
    float ulc = 1.0f, uls = 0.0f;
    if (lane < 12) {
        __sincosf(qw[lane] * 0.5f, &uls, &ulc);
    }
    float cw[12], sw[12];
#pragma unroll
    for (int k = 0; k < 12; ++k) {
        cw[k] = bcast_lane(ulc, k);
        sw[k] = bcast_lane(uls, k);
    }

    // --- data-encoding angles (coalesced float4 load) ---
    float4 xv = reinterpret_cast<const float4*>(x)[b];
    float cx[4], sx[4];
    __sincosf(xv.x * 0.5f, &sx[0], &cx[0]);
    __sincosf(xv.y * 0.5f, &sx[1], &cx[1]);
    __sincosf(xv.z * 0.5f, &sx[2], &cx[2]);
    __sincosf(xv.w * 0.5f, &sx[3], &cx[3]);

    // --- initial product state after 4 data RYs on |0000> ---
    float a01[4] = { cx[0]*cx[1], cx[0]*sx[1], sx[0]*cx[1], sx[0]*sx[1] };
    float a23[4] = { cx[2]*cx[3], cx[2]*sx[3], sx[2]*cx[3], sx[2]*sx[3] };
    float s[16];
#pragma unroll
    for (int i = 0; i < 16; ++i) s[i] = a01[i >> 2] * a23[i & 3];

    // --- the 3 trainable layers + entanglers ---
    run_circuit(s, cw, sw);

    // --- probabilities ---
    float p[16];
#pragma unroll
    for (int i = 0; i < 16; ++i) p[i] = s[i] * s[i];

    // --- <Z_q> via Walsh-Hadamard-style butterfly ---
    float q3p[8], q3m[8];
#pragma unroll
    for (int i = 0; i < 8; ++i) { q3p[i] = p[i] + p[i + 8]; q3m[i] = p[i] - p[i + 8]; }
    float z0 = ((q3m[0] + q3m[1]) + (q3m[2] + q3m[3]))
             + ((q3m[4] + q3m[5]) + (q3m[6] + q3m[7]));
    float q2p[4], q2m[4];
#pragma unroll
    for (int i = 0; i < 4; ++i) { q2p[i] = q3p[i] + q3p[i + 4]; q2m[i] = q3p[i] - q3p[i + 4]; }
    float z1 = (q2m[0] + q2m[1]) + (q2m[2] + q2m[3]);
    float q1p[2], q1m[2];
#pragma unroll
    for (int i = 0; i < 2; ++i) { q1p[i] = q2p[i] + q2p[i + 2]; q1m[i] = q2p[i] - q2p[i + 2]; }
    float z2 = q1m[0] + q1m[1];
    float z3 = q1p[0] - q1p[1];
    float z[4] = { z0, z1, z2, z3 };

    // --- linear [6,4] + bias (uniform weights -> scalar loads) ---
    float logits[6];
#pragma unroll
    for (int j = 0; j < 6; ++j) {
        logits[j] = bias[j]
                  + z[0] * W[4*j + 0]
                  + z[1] * W[4*j + 1]
                  + z[2] * W[4*j + 2]
                  + z[3] * W[4*j + 3];
    }

    // --- softmax; logits bounded so no max-subtraction needed ---
    float e[6], sum = 0.0f;
#pragma unroll
    for (int j = 0; j < 6; ++j) {
        e[j] = __expf(logits[j]);
        sum += e[j];
    }
    float inv = __frcp_rn(sum);

    float2* o2 = reinterpret_cast<float2*>(out + (size_t)b * 6);
    o2[0] = make_float2(e[0] * inv, e[1] * inv);
    o2[1] = make_float2(e[2] * inv, e[3] * inv);
    o2[2] = make_float2(e[4] * inv, e[5] * inv);

    // ================= MEASUREMENT PROBE (sunk, output-invariant) ==========
    // Placed AFTER the store so s[]/p[] are dead and registers are reused.
    // Perturbed inputs (xv + off) prevent CSE with the real pass; asm sinks
    // prevent DCE (rule #17). Each pass ~= 425 VALU ops ~= the real circuit.
#pragma unroll
    for (int pp = 0; pp < PROBE_PASSES; ++pp) {
        float off = 0.3f + 0.7f * (float)pp;
        float cxp[4], sxp[4];
        __sincosf(xv.x * 0.5f + off, &sxp[0], &cxp[0]);
        __sincosf(xv.y * 0.5f + off, &sxp[1], &cxp[1]);
        __sincosf(xv.z * 0.5f + off, &sxp[2], &cxp[2]);
        __sincosf(xv.w * 0.5f + off, &sxp[3], &cxp[3]);
        float a01p[4] = { cxp[0]*cxp[1], cxp[0]*sxp[1], sxp[0]*cxp[1], sxp[0]*sxp[1] };
        float a23p[4] = { cxp[2]*cxp[3], cxp[2]*sxp[3], sxp[2]*cxp[3], sxp[2]*sxp[3] };
        float sp[16];
#pragma unroll
        for (int i = 0; i < 16; ++i) sp[i] = a01p[i >> 2] * a23p[i & 3];
        run_circuit(sp, cw, sw);
#pragma unroll
        for (int i = 0; i < 16; ++i) asm volatile("" :: "v"(sp[i]));
    }
    // =======================================================================
}

extern "C" void kernel_launch(void* const* d_in, const int* in_sizes, int n_in,
                              void* d_out, int out_size, void* d_ws, size_t ws_size,
                              hipStream_t stream) {
    const float* x    = (const float*)d_in[0];
    const float* qw   = (const float*)d_in[1];
    const float* W    = (const float*)d_in[2];
    const float* bias = (const float*)d_in[3];
    float* out = (float*)d_out;

    int B = in_sizes[0] / 4;
    int block = 256;
    int grid = (B + block - 1) / block;
    qnn_kernel<<<grid, block, 0, stream>>>(x, qw, W, bias, out, B);
}

// Round 4
// 73.035 us; speedup vs baseline: 1.1338x; 1.1338x over previous
//
#include <hip/hip_runtime.h>
#include <math.h>

// 4-qubit real statevector QNN, one thread per sample.
// Qubit q's bit in state index i is (i >> (3-q)) & 1 (wire 0 = MSB, matching
// the reference's reshape [B, 2^q, 2, 2^(3-q)]).
//
// STATUS (round 3): kernel body measured at ~4-6 us via the round-2/3
// dead-work probe (+7.4 us for 2x extra circuit = 3.7 us/pass, ~80% of the
// VALU throughput model). The 75 us timed region is dominated by the
// harness's 268 MB reset fill (~42 us @ 80% HBM peak) + small dispatches —
// outside this file's control. Kernel is within ~25% of its own VALU/HBM
// roofline; further body optimization is below session noise (+/- 2 us).

template <int Q>
__device__ __forceinline__ void apply_ry(float* s, float c, float sn) {
    constexpr int stride = 1 << (3 - Q);
#pragma unroll
    for (int i = 0; i < 16; ++i) {
        if (!(i & stride)) {
            float a0 = s[i];
            float a1 = s[i + stride];
            s[i]          = c * a0 - sn * a1;
            s[i + stride] = sn * a0 + c * a1;
        }
    }
}

template <int C, int T>
__device__ __forceinline__ void cnot_(float* s) {
    // pure register permutation — zero instructions after regalloc
    constexpr int cs = 1 << (3 - C);
    constexpr int ts = 1 << (3 - T);
#pragma unroll
    for (int i = 0; i < 16; ++i) {
        if ((i & cs) && !(i & ts)) {
            float tmp = s[i];
            s[i] = s[i + ts];
            s[i + ts] = tmp;
        }
    }
}

__device__ __forceinline__ float bcast_lane(float v, int lane) {
    return __int_as_float(__builtin_amdgcn_readlane(__float_as_int(v), lane));
}

__global__ __launch_bounds__(256) void qnn_kernel(
    const float* __restrict__ x,     // [B,4]
    const float* __restrict__ qw,    // [3,4] trainable angles (uniform)
    const float* __restrict__ W,     // [6,4]
    const float* __restrict__ bias,  // [6]
    float* __restrict__ out,         // [B,6]
    int B)
{
    int b = blockIdx.x * blockDim.x + threadIdx.x;
    if (b >= B) return;
    int lane = threadIdx.x & 63;

    // --- uniform trainable-angle trig: lanes 0..11 each do ONE sincos,
    //     broadcast via readlane -> SGPR-resident uniforms ---
    float ulc = 1.0f, uls = 0.0f;
    if (lane < 12) {
        __sincosf(qw[lane] * 0.5f, &uls, &ulc);
    }
    float cw[12], sw[12];
#pragma unroll
    for (int k = 0; k < 12; ++k) {
        cw[k] = bcast_lane(ulc, k);
        sw[k] = bcast_lane(uls, k);
    }

    // --- data-encoding angles (coalesced float4 load) ---
    float4 xv = reinterpret_cast<const float4*>(x)[b];
    float cx[4], sx[4];
    __sincosf(xv.x * 0.5f, &sx[0], &cx[0]);
    __sincosf(xv.y * 0.5f, &sx[1], &cx[1]);
    __sincosf(xv.z * 0.5f, &sx[2], &cx[2]);
    __sincosf(xv.w * 0.5f, &sx[3], &cx[3]);

    // --- initial product state after 4 data RYs on |0000> ---
    float a01[4] = { cx[0]*cx[1], cx[0]*sx[1], sx[0]*cx[1], sx[0]*sx[1] };
    float a23[4] = { cx[2]*cx[3], cx[2]*sx[3], sx[2]*cx[3], sx[2]*sx[3] };
    float s[16];
#pragma unroll
    for (int i = 0; i < 16; ++i) s[i] = a01[i >> 2] * a23[i & 3];

    // --- layer 0 ---
    apply_ry<0>(s, cw[0], sw[0]);
    apply_ry<1>(s, cw[1], sw[1]);
    apply_ry<2>(s, cw[2], sw[2]);
    apply_ry<3>(s, cw[3], sw[3]);
    cnot_<0,1>(s); cnot_<1,2>(s); cnot_<2,3>(s); cnot_<3,0>(s);

    // --- layer 1 ---
    apply_ry<0>(s, cw[4], sw[4]);
    apply_ry<1>(s, cw[5], sw[5]);
    apply_ry<2>(s, cw[6], sw[6]);
    apply_ry<3>(s, cw[7], sw[7]);
    cnot_<0,1>(s); cnot_<1,2>(s); cnot_<2,3>(s); cnot_<3,0>(s);

    // --- layer 2 (no entangler after) ---
    apply_ry<0>(s, cw[8],  sw[8]);
    apply_ry<1>(s, cw[9],  sw[9]);
    apply_ry<2>(s, cw[10], sw[10]);
    apply_ry<3>(s, cw[11], sw[11]);

    // --- probabilities ---
    float p[16];
#pragma unroll
    for (int i = 0; i < 16; ++i) p[i] = s[i] * s[i];

    // --- <Z_q> via Walsh-Hadamard-style butterfly (41 adds vs 60) ---
    // qubit 0 <-> bit3 (stride 8), qubit 3 <-> bit0 (stride 1)
    float q3p[8], q3m[8];
#pragma unroll
    for (int i = 0; i < 8; ++i) { q3p[i] = p[i] + p[i + 8]; q3m[i] = p[i] - p[i + 8]; }
    float z0 = ((q3m[0] + q3m[1]) + (q3m[2] + q3m[3]))
             + ((q3m[4] + q3m[5]) + (q3m[6] + q3m[7]));
    float q2p[4], q2m[4];
#pragma unroll
    for (int i = 0; i < 4; ++i) { q2p[i] = q3p[i] + q3p[i + 4]; q2m[i] = q3p[i] - q3p[i + 4]; }
    float z1 = (q2m[0] + q2m[1]) + (q2m[2] + q2m[3]);
    float q1p[2], q1m[2];
#pragma unroll
    for (int i = 0; i < 2; ++i) { q1p[i] = q2p[i] + q2p[i + 2]; q1m[i] = q2p[i] - q2p[i + 2]; }
    float z2 = q1m[0] + q1m[1];
    float z3 = q1p[0] - q1p[1];
    float z[4] = { z0, z1, z2, z3 };

    // --- linear [6,4] + bias (uniform weights -> scalar loads) ---
    float logits[6];
#pragma unroll
    for (int j = 0; j < 6; ++j) {
        logits[j] = bias[j]
                  + z[0] * W[4*j + 0]
                  + z[1] * W[4*j + 1]
                  + z[2] * W[4*j + 2]
                  + z[3] * W[4*j + 3];
    }

    // --- softmax; logits bounded (|z|<=1, small W) so no max-subtraction needed ---
    float e[6], sum = 0.0f;
#pragma unroll
    for (int j = 0; j < 6; ++j) {
        e[j] = __expf(logits[j]);
        sum += e[j];
    }
    float inv = __frcp_rn(sum);

    // --- store: b*6 floats = 24 B, always 8-aligned -> 3x float2 ---
    float2* o2 = reinterpret_cast<float2*>(out + (size_t)b * 6);
    o2[0] = make_float2(e[0] * inv, e[1] * inv);
    o2[1] = make_float2(e[2] * inv, e[3] * inv);
    o2[2] = make_float2(e[4] * inv, e[5] * inv);
}

extern "C" void kernel_launch(void* const* d_in, const int* in_sizes, int n_in,
                              void* d_out, int out_size, void* d_ws, size_t ws_size,
                              hipStream_t stream) {
    const float* x    = (const float*)d_in[0];
    const float* qw   = (const float*)d_in[1];
    const float* W    = (const float*)d_in[2];
    const float* bias = (const float*)d_in[3];
    float* out = (float*)d_out;

    int B = in_sizes[0] / 4;
    int block = 256;
    int grid = (B + block - 1) / block;
    qnn_kernel<<<grid, block, 0, stream>>>(x, qw, W, bias, out, B);
}